// Round 7
// baseline (242.007 us; speedup 1.0000x reference)
//
#include <hip/hip_runtime.h>

#define DIM 4096
#define HAD_SCALE 0.015625f  // 1/sqrt(4096) = 1/64

// Native clang vector type: __builtin_nontemporal_store requires a pointer
// to scalar/vector-of-scalar, NOT HIP's float4 class type.
typedef float floatx4 __attribute__((ext_vector_type(4)));

// DPP quad_perm lane shuffle (VALU pipe). 0xB1 = lane^1, 0x4E = lane^2.
template <int CTRL>
__device__ __forceinline__ float qperm(float v) {
    return __int_as_float(
        __builtin_amdgcn_mov_dpp(__float_as_int(v), CTRL, 0xF, 0xF, false));
}

// ds_swizzle bit-mode lane xor (LDS pipe, no LDS storage). offset encoding:
// (xor<<10)|(or<<5)|and, and=0x1F. xor4=0x101F, xor8=0x201F, xor16=0x401F.
template <int OFS>
__device__ __forceinline__ float lswz(float v) {
    return __int_as_float(
        __builtin_amdgcn_ds_swizzle(__float_as_int(v), OFS));
}

struct Signs { float sA, sB, sC, sD, sE, sF; };

// ---- verified-bit-exact row pieces (identical math to rounds 4/5, both of
// which measured absmax = 0.0) ----

__device__ __forceinline__ void loadRow(const float4* __restrict__ x4,
                                        int lane, float r[64]) {
#pragma unroll
    for (int g = 0; g < 16; g++) {
        float4 v = x4[g * 64 + lane];
        r[4 * g + 0] = v.x;
        r[4 * g + 1] = v.y;
        r[4 * g + 2] = v.z;
        r[4 * g + 3] = v.w;
    }
}

// Bit schedule (12 j-bits, each exactly once), j = e + 4*lane + 256*g:
//   in-register fwht        : bits {0,1}   (e)
//   DPP quad_perm xor1/xor2 : bits {2,3}   (lane bits 0,1)
//   ds_swizzle xor4/8/16    : bits {4,5,6} (lane bits 2,3,4)
//   shfl_xor 32             : bit  {7}     (lane bit 5)
//   in-register fwht        : bits {8..11} (g)
__device__ __forceinline__ void computeRow(float r[64], const Signs& s) {
#pragma unroll
    for (int g = 0; g < 16; g++) {
        {   // bits {0,1}: 2x2 fwht within the float4
            float a = r[4 * g + 0], b = r[4 * g + 1];
            float c = r[4 * g + 2], d = r[4 * g + 3];
            float ab0 = a + b, ab1 = a - b;
            float cd0 = c + d, cd1 = c - d;
            r[4 * g + 0] = ab0 + cd0;
            r[4 * g + 1] = ab1 + cd1;
            r[4 * g + 2] = ab0 - cd0;
            r[4 * g + 3] = ab1 - cd1;
        }
#pragma unroll
        for (int e = 0; e < 4; e++) {   // bits {2..7}: cross-lane chain
            float v = r[4 * g + e];
            v = __builtin_fmaf(v, s.sA, qperm<0xB1>(v));        // j bit 2
            v = __builtin_fmaf(v, s.sB, qperm<0x4E>(v));        // j bit 3
            v = __builtin_fmaf(v, s.sC, lswz<0x101F>(v));       // j bit 4
            v = __builtin_fmaf(v, s.sD, lswz<0x201F>(v));       // j bit 5
            v = __builtin_fmaf(v, s.sE, lswz<0x401F>(v));       // j bit 6
            v = __builtin_fmaf(v, s.sF, __shfl_xor(v, 32, 64)); // j bit 7
            r[4 * g + e] = v;
        }
    }
    // bits {8..11}: fwht over the group index (static indices only)
#pragma unroll
    for (int st = 4; st < 64; st <<= 1) {
#pragma unroll
        for (int i = 0; i < 64; i++) {
            if ((i & st) == 0) {
                float a = r[i];
                float b = r[i ^ st];
                r[i]      = a + b;
                r[i ^ st] = a - b;
            }
        }
    }
}

// Non-temporal store: y is never re-read by the kernel; the 'nt' flag keeps
// the 128 MiB write stream from evicting x out of L3 (x is re-read every
// bench iteration - FETCH_SIZE=65MB showed half of x falling out of L3).
__device__ __forceinline__ void storeRowNT(floatx4* __restrict__ y4,
                                           int lane, const float r[64]) {
#pragma unroll
    for (int g = 0; g < 16; g++) {
        floatx4 v;
        v.x = r[4 * g + 0] * HAD_SCALE;
        v.y = r[4 * g + 1] * HAD_SCALE;
        v.z = r[4 * g + 2] * HAD_SCALE;
        v.w = r[4 * g + 3] * HAD_SCALE;
        __builtin_nontemporal_store(v, &y4[g * 64 + lane]);
    }
}

// PERSISTENT WAVES, 4 rows/wave, 2-deep software pipeline with FOUR named
// row buffers (A,B,C,D - static indexing only, so everything stays in VGPRs).
// Program order issues the NEXT row's 16 loads before the CURRENT row's
// compute; sched_barrier(0) pins that order (round 5 proved the compiler
// otherwise sinks the prefetch and re-creates the load->compute->store
// convoy: VGPR=80 instead of >=140).
// Distinct buffers also avoid a WAR-vmcnt stall between storeRowNT(A) and
// the next load (fresh registers, no physical reuse needed).
__global__ __launch_bounds__(256) void fwht_kernel(const float* __restrict__ x,
                                                   float* __restrict__ y,
                                                   int nwaves) {
    const int t = threadIdx.x;
    const int lane = t & 63;
    const int wid = blockIdx.x * 4 + (t >> 6);   // 0..nwaves-1

    const float4* __restrict__ x0 = (const float4*)(x + (size_t)wid * DIM);
    floatx4* __restrict__ y0 = (floatx4*)(y + (size_t)wid * DIM);
    const size_t stride4 = (size_t)nwaves * (DIM / 4);  // row stride in float4

    Signs s;
    s.sA = (lane & 1)  ? -1.f : 1.f;
    s.sB = (lane & 2)  ? -1.f : 1.f;
    s.sC = (lane & 4)  ? -1.f : 1.f;
    s.sD = (lane & 8)  ? -1.f : 1.f;
    s.sE = (lane & 16) ? -1.f : 1.f;
    s.sF = (lane & 32) ? -1.f : 1.f;

    float A[64], B[64], C[64], D[64];

    loadRow(x0, lane, A);                 // row 0 in flight
    loadRow(x0 + stride4, lane, B);       // row 1 in flight (32 KiB total)
    __builtin_amdgcn_sched_barrier(0);    // do NOT sink B's loads
    computeRow(A, s);
    storeRowNT(y0, lane, A);
    loadRow(x0 + 2 * stride4, lane, C);   // row 2 in flight during B compute
    __builtin_amdgcn_sched_barrier(0);
    computeRow(B, s);
    storeRowNT(y0 + stride4, lane, B);
    loadRow(x0 + 3 * stride4, lane, D);   // row 3 in flight during C compute
    __builtin_amdgcn_sched_barrier(0);
    computeRow(C, s);
    storeRowNT(y0 + 2 * stride4, lane, C);
    computeRow(D, s);
    storeRowNT(y0 + 3 * stride4, lane, D);
}

extern "C" void kernel_launch(void* const* d_in, const int* in_sizes, int n_in,
                              void* d_out, int out_size, void* d_ws, size_t ws_size,
                              hipStream_t stream) {
    const float* x = (const float*)d_in[0];
    float* y = (float*)d_out;
    const int n = in_sizes[0];
    const int rows = n / DIM;        // 8192 for (4, 2048, 4096)
    const int nwaves = rows / 4;     // 2048 persistent waves, 4 rows each
    fwht_kernel<<<nwaves / 4, 256, 0, stream>>>(x, y, nwaves);
}

// Round 8
// 235.661 us; speedup vs baseline: 1.0269x; 1.0269x over previous
//
#include <hip/hip_runtime.h>

#define DIM 4096
#define HAD_SCALE 0.015625f  // 1/sqrt(4096) = 1/64

// DPP quad_perm lane shuffle (VALU pipe). 0xB1 = lane^1, 0x4E = lane^2.
template <int CTRL>
__device__ __forceinline__ float qperm(float v) {
    return __int_as_float(
        __builtin_amdgcn_mov_dpp(__float_as_int(v), CTRL, 0xF, 0xF, false));
}

// ds_swizzle bit-mode lane xor (LDS pipe, no LDS storage). offset encoding:
// (xor<<10)|(or<<5)|and, and=0x1F. xor4=0x101F, xor8=0x201F, xor16=0x401F.
template <int OFS>
__device__ __forceinline__ float lswz(float v) {
    return __int_as_float(
        __builtin_amdgcn_ds_swizzle(__float_as_int(v), OFS));
}

struct Signs { float sA, sB, sC, sD, sE, sF; };

// ---- verified-bit-exact row pieces (identical math to rounds 4/5/7, all of
// which measured absmax = 0.0) ----

__device__ __forceinline__ void loadRow(const float4* __restrict__ x4,
                                        int lane, float r[64]) {
#pragma unroll
    for (int g = 0; g < 16; g++) {
        float4 v = x4[g * 64 + lane];
        r[4 * g + 0] = v.x;
        r[4 * g + 1] = v.y;
        r[4 * g + 2] = v.z;
        r[4 * g + 3] = v.w;
    }
}

// Bit schedule (12 j-bits, each exactly once), j = e + 4*lane + 256*g:
//   in-register fwht        : bits {0,1}   (e)
//   DPP quad_perm xor1/xor2 : bits {2,3}   (lane bits 0,1)
//   ds_swizzle xor4/8/16    : bits {4,5,6} (lane bits 2,3,4)
//   shfl_xor 32             : bit  {7}     (lane bit 5)
//   in-register fwht        : bits {8..11} (g)
__device__ __forceinline__ void computeRow(float r[64], const Signs& s) {
#pragma unroll
    for (int g = 0; g < 16; g++) {
        {   // bits {0,1}: 2x2 fwht within the float4
            float a = r[4 * g + 0], b = r[4 * g + 1];
            float c = r[4 * g + 2], d = r[4 * g + 3];
            float ab0 = a + b, ab1 = a - b;
            float cd0 = c + d, cd1 = c - d;
            r[4 * g + 0] = ab0 + cd0;
            r[4 * g + 1] = ab1 + cd1;
            r[4 * g + 2] = ab0 - cd0;
            r[4 * g + 3] = ab1 - cd1;
        }
#pragma unroll
        for (int e = 0; e < 4; e++) {   // bits {2..7}: cross-lane chain
            float v = r[4 * g + e];
            v = __builtin_fmaf(v, s.sA, qperm<0xB1>(v));        // j bit 2
            v = __builtin_fmaf(v, s.sB, qperm<0x4E>(v));        // j bit 3
            v = __builtin_fmaf(v, s.sC, lswz<0x101F>(v));       // j bit 4
            v = __builtin_fmaf(v, s.sD, lswz<0x201F>(v));       // j bit 5
            v = __builtin_fmaf(v, s.sE, lswz<0x401F>(v));       // j bit 6
            v = __builtin_fmaf(v, s.sF, __shfl_xor(v, 32, 64)); // j bit 7
            r[4 * g + e] = v;
        }
    }
    // bits {8..11}: fwht over the group index (static indices only)
#pragma unroll
    for (int st = 4; st < 64; st <<= 1) {
#pragma unroll
        for (int i = 0; i < 64; i++) {
            if ((i & st) == 0) {
                float a = r[i];
                float b = r[i ^ st];
                r[i]      = a + b;
                r[i ^ st] = a - b;
            }
        }
    }
}

// Normal (cached) stores: round 7 proved NT stores put store-completion on
// the critical path (vmcnt drains at HBM pace instead of L2 pace) -> 123 us.
__device__ __forceinline__ void storeRow(float4* __restrict__ y4,
                                         int lane, const float r[64]) {
#pragma unroll
    for (int g = 0; g < 16; g++)
        y4[g * 64 + lane] = make_float4(r[4 * g + 0] * HAD_SCALE,
                                        r[4 * g + 1] * HAD_SCALE,
                                        r[4 * g + 2] * HAD_SCALE,
                                        r[4 * g + 3] * HAD_SCALE);
}

// TWO ROWS PER WAVE, depth-2 pinned pipeline, NORMAL stores.
//   loads A + loads B (32 KiB in flight) | compute A, store A | compute B, store B
// sched_barrier(0) keeps B's loads issued ahead of A's compute (round 5:
// without the pin the compiler sinks them, VGPR 80 = convoy restored).
// Grid: 4096 waves (1024 blocks) -> 4 waves/SIMD supplied; VGPR ~150 caps
// at 3/SIMD, so the machine stays fully fed (round 7 under-supplied at 2).
__global__ __launch_bounds__(256) void fwht_kernel(const float* __restrict__ x,
                                                   float* __restrict__ y,
                                                   int nwaves) {
    const int t = threadIdx.x;
    const int lane = t & 63;
    const int wid = blockIdx.x * 4 + (t >> 6);   // 0..nwaves-1

    const float4* __restrict__ xA = (const float4*)(x + (size_t)wid * DIM);
    float4* __restrict__ yA = (float4*)(y + (size_t)wid * DIM);
    const size_t stride4 = (size_t)nwaves * (DIM / 4);  // row stride in float4

    Signs s;
    s.sA = (lane & 1)  ? -1.f : 1.f;
    s.sB = (lane & 2)  ? -1.f : 1.f;
    s.sC = (lane & 4)  ? -1.f : 1.f;
    s.sD = (lane & 8)  ? -1.f : 1.f;
    s.sE = (lane & 16) ? -1.f : 1.f;
    s.sF = (lane & 32) ? -1.f : 1.f;

    float A[64], B[64];

    loadRow(xA, lane, A);                 // row A in flight (16 KiB)
    loadRow(xA + stride4, lane, B);       // row B in flight (32 KiB total)
    __builtin_amdgcn_sched_barrier(0);    // do NOT sink B's loads below this
    computeRow(A, s);                     // waits only on A (vmcnt(16))
    storeRow(yA, lane, A);                // absorbs into L2, drains fast
    __builtin_amdgcn_sched_barrier(0);
    computeRow(B, s);                     // B landed during computeRow(A)
    storeRow(yA + stride4, lane, B);
}

extern "C" void kernel_launch(void* const* d_in, const int* in_sizes, int n_in,
                              void* d_out, int out_size, void* d_ws, size_t ws_size,
                              hipStream_t stream) {
    const float* x = (const float*)d_in[0];
    float* y = (float*)d_out;
    const int n = in_sizes[0];
    const int rows = n / DIM;        // 8192 for (4, 2048, 4096)
    const int nwaves = rows / 2;     // 4096 waves, 2 rows each
    fwht_kernel<<<nwaves / 4, 256, 0, stream>>>(x, y, nwaves);
}